// Round 13
// baseline (528.174 us; speedup 1.0000x reference)
//
#include <hip/hip_runtime.h>

// ---------------------------------------------------------------------------
// TiedRowAxialAttention on MI355X (gfx950), bf16 MFMA pipeline.
// dims: b=4 rows=64 t=256 dim=512 heads=8 dim_head=64 ; scale = 1/64
// stages:
//   cast_x: x -> bf16 (xb)
//   prep:   W_qkv permuted (d,k,h)->(k,h,d) + bf16 ; W0->bf16   (one kernel)
//   gemm1:  qkv = xb @ Wp^T -> Q[bh][i][rd], K[bh][j][rd], Vt[bh][rd][j]
//           PERSISTENT blocks: 4 m-tiles per block, flat 64-iter ring (fill
//           cost 12% -> 3%); acc flushed at tile boundaries after the barrier.
//   gemm_s: S[bh][i][j] partials (split-K=4) -> BF16 (halved traffic);
//           XCD-grouped so one bh's 8 blocks share an XCD L2.
//   softmax: wave-per-row over 4 bf16 partials, P = softmax(S/64) bf16.
//   gemm_pv: O = P V via A=Vt,B=P -> O2[(b,r,i)][hd]
//   gemm2:  out = O2 @ W0^T -> fp32 (2 m-tiles per block)
// GEMM mainloop (R7-proven): 256x128 tile, BK=32, 4 waves (2Mx2N, per-wave
// 128x64, acc[8][4]), 3 LDS buffers (72 KB, 2 blk/CU), 2-tile prefetch lead,
// counted vmcnt(6) (never 0 mid-loop), one barrier per K-tile.
// ---------------------------------------------------------------------------

typedef short  bf16x8 __attribute__((ext_vector_type(8)));
typedef float  f32x4  __attribute__((ext_vector_type(4)));

#define MFMA16(a,b,c) __builtin_amdgcn_mfma_f32_16x16x32_bf16((a),(b),(c),0,0,0)

__device__ __forceinline__ ushort f2bf(float f) {
  union { float f; unsigned u; } v; v.f = f;
  unsigned r = v.u + 0x7fffu + ((v.u >> 16) & 1u);   // RNE
  return (ushort)(r >> 16);
}

__device__ __forceinline__ float bf2f(ushort u) {
  union { unsigned u; float f; } v; v.u = ((unsigned)u) << 16;
  return v.f;
}

__device__ __forceinline__ void gload_lds16(const void* g, void* lds) {
  __builtin_amdgcn_global_load_lds(
      (const __attribute__((address_space(1))) void*)g,
      (__attribute__((address_space(3))) void*)lds, 16, 0, 0);
}

// -------------------------------- prep -------------------------------------

__global__ void cast_f32_to_bf16(const float* __restrict__ in,
                                 ushort* __restrict__ out, int n4) {
  int idx = blockIdx.x * blockDim.x + threadIdx.x;
  int stride = gridDim.x * blockDim.x;
  for (int v = idx; v < n4; v += stride) {
    float4 f = reinterpret_cast<const float4*>(in)[v];
    ushort4 o; o.x = f2bf(f.x); o.y = f2bf(f.y); o.z = f2bf(f.z); o.w = f2bf(f.w);
    reinterpret_cast<ushort4*>(out)[v] = o;
  }
}

// blocks 0..767: permute W_qkv (2 rows per block); blocks 768..831: cast W0.
__global__ void prep_k(const float* __restrict__ W, ushort* __restrict__ Wp,
                       const float* __restrict__ W0, ushort* __restrict__ W0b) {
  const int bid = blockIdx.x, tid = threadIdx.x;
  if (bid < 768) {
    int np = (bid << 1) + (tid >> 7);       // 0..1535
    int c  = tid & 127;
    int k = np >> 9, h = (np >> 6) & 7, d = np & 63;
    float4 f = reinterpret_cast<const float4*>(
        W + (size_t)(d * 24 + k * 8 + h) * 512)[c];
    ushort4 u; u.x = f2bf(f.x); u.y = f2bf(f.y); u.z = f2bf(f.z); u.w = f2bf(f.w);
    reinterpret_cast<ushort4*>(Wp + (size_t)np * 512)[c] = u;
  } else {
    int v0 = ((bid - 768) << 10) + (tid << 2);    // 64 blocks x 1024 f4
#pragma unroll
    for (int q = 0; q < 4; ++q) {
      int v = v0 + q;
      float4 f = reinterpret_cast<const float4*>(W0)[v];
      ushort4 u; u.x = f2bf(f.x); u.y = f2bf(f.y); u.z = f2bf(f.z); u.w = f2bf(f.w);
      reinterpret_cast<ushort4*>(W0b)[v] = u;
    }
  }
}

// ================== 256x128 pipelined NT mainloop (4 waves) =================
// (generic single-tile version: gemm_s / gemm_pv)

__device__ __forceinline__ void gemm_nt_256x128(
    const ushort* __restrict__ A, const ushort* __restrict__ B,
    int lda, int ldb, int P, int m0, int n0, char* lds, f32x4 (&acc)[8][4]) {
  const int tid = threadIdx.x;
  const int w = tid >> 6, l = tid & 63;
  const int il = l & 15, kl = l >> 4;
  const int wm = w >> 1, wn = w & 1;

  auto stageA = [&](char* buf, int kt) {
#pragma unroll
    for (int c = 0; c < 4; ++c) {
      int rbase = (w << 6) + (c << 4);
      int row = rbase + (l >> 2);
      int s = ((l & 3) - ((row >> 1) & 3)) & 3;
      gload_lds16(A + (size_t)(m0 + row) * lda + (kt << 5) + (s << 3),
                  buf + rbase * 64);
    }
  };
  auto stageB = [&](char* buf, int kt) {
#pragma unroll
    for (int c = 0; c < 2; ++c) {
      int rbase = (w << 5) + (c << 4);
      int row = rbase + (l >> 2);
      int s = ((l & 3) - ((row >> 1) & 3)) & 3;
      gload_lds16(B + (size_t)(n0 + row) * ldb + (kt << 5) + (s << 3),
                  buf + 16384 + rbase * 64);
    }
  };
  auto loadA8 = [&](const char* buf, bf16x8 (&af)[8]) {
#pragma unroll
    for (int q = 0; q < 8; ++q) {
      int row = (wm << 7) + (q << 4) + il;
      af[q] = *(const bf16x8*)(buf + row * 64 + (((kl + (row >> 1)) & 3) << 4));
    }
  };
  auto loadB4 = [&](const char* buf, bf16x8 (&bfr)[4]) {
#pragma unroll
    for (int q = 0; q < 4; ++q) {
      int row = (wn << 6) + (q << 4) + il;
      bfr[q] = *(const bf16x8*)(buf + 16384 + row * 64 + (((kl + (row >> 1)) & 3) << 4));
    }
  };

#pragma unroll
  for (int i = 0; i < 8; ++i)
#pragma unroll
    for (int j = 0; j < 4; ++j) acc[i][j] = f32x4{0.f, 0.f, 0.f, 0.f};

  stageA(lds, 0);         stageB(lds, 0);
  stageA(lds + 24576, 1); stageB(lds + 24576, 1);
  asm volatile("s_waitcnt vmcnt(6)" ::: "memory");
  __builtin_amdgcn_s_barrier();

  int cur = 0, nx = 2;
  for (int g = 0; g < P; ++g) {
    char* cbuf = lds + cur * 24576;
    char* sbuf = lds + nx * 24576;
    bf16x8 af[8], bfr[4];
    loadA8(cbuf, af);
    loadB4(cbuf, bfr);
    if (g + 2 < P) { stageA(sbuf, g + 2); stageB(sbuf, g + 2); }
    __builtin_amdgcn_s_setprio(1);
#pragma unroll
    for (int fm = 0; fm < 8; ++fm)
#pragma unroll
      for (int fn = 0; fn < 4; ++fn)
        acc[fm][fn] = MFMA16(af[fm], bfr[fn], acc[fm][fn]);
    __builtin_amdgcn_s_setprio(0);
    if (g + 2 < P) asm volatile("s_waitcnt vmcnt(6)" ::: "memory");
    else           asm volatile("s_waitcnt vmcnt(0)" ::: "memory");
    __builtin_amdgcn_s_barrier();
    cur = (cur == 2) ? 0 : cur + 1;
    nx  = (nx  == 2) ? 0 : nx  + 1;
  }
}

// ------------------------------- gemm1 (qkv) --------------------------------
// 768 persistent blocks; each does 4 m-tiles x 16 K-tiles = 64 flat ring iters.
// XCD swizzle: 12 n-blocks of one panel group co-XCD. Flush at tile bounds.

__global__ __launch_bounds__(256, 2) void gemm_qkv_k(
    const ushort* __restrict__ xb, const ushort* __restrict__ Wp,
    ushort* __restrict__ Qb, ushort* __restrict__ Kb, ushort* __restrict__ Vt) {
  __shared__ __align__(16) char lds_s[73728];
  char* lds = lds_s;
  f32x4 acc[8][4];
  const int Bid = blockIdx.x;
  const int xcd = Bid & 7, idx = Bid >> 3;
  const int nt = idx % 12, pg = idx / 12;       // pg 0..7
  const int n0 = nt << 7;
  const int kq = n0 >> 9;                       // block-uniform: 0=Q 1=K 2=V

  const int tid = threadIdx.x, w = tid >> 6, l = tid & 63;
  const int il = l & 15, kl = l >> 4;
  const int wm = w >> 1, wn = w & 1;

  auto mtile_of = [&](int j) { return (((pg << 2) + (j >> 4)) << 3) + xcd; };

  auto stageA = [&](char* buf, int j) {
    const size_t m0j = (size_t)mtile_of(j) << 8;
    const int kt = j & 15;
#pragma unroll
    for (int c = 0; c < 4; ++c) {
      int rbase = (w << 6) + (c << 4);
      int row = rbase + (l >> 2);
      int s = ((l & 3) - ((row >> 1) & 3)) & 3;
      gload_lds16(xb + (m0j + row) * 512 + (kt << 5) + (s << 3),
                  buf + rbase * 64);
    }
  };
  auto stageB = [&](char* buf, int j) {
    const int kt = j & 15;
#pragma unroll
    for (int c = 0; c < 2; ++c) {
      int rbase = (w << 5) + (c << 4);
      int row = rbase + (l >> 2);
      int s = ((l & 3) - ((row >> 1) & 3)) & 3;
      gload_lds16(Wp + (size_t)(n0 + row) * 512 + (kt << 5) + (s << 3),
                  buf + 16384 + rbase * 64);
    }
  };
  auto loadA8 = [&](const char* buf, bf16x8 (&af)[8]) {
#pragma unroll
    for (int q = 0; q < 8; ++q) {
      int row = (wm << 7) + (q << 4) + il;
      af[q] = *(const bf16x8*)(buf + row * 64 + (((kl + (row >> 1)) & 3) << 4));
    }
  };
  auto loadB4 = [&](const char* buf, bf16x8 (&bfr)[4]) {
#pragma unroll
    for (int q = 0; q < 4; ++q) {
      int row = (wn << 6) + (q << 4) + il;
      bfr[q] = *(const bf16x8*)(buf + 16384 + row * 64 + (((kl + (row >> 1)) & 3) << 4));
    }
  };
  auto flush = [&](int mt) {                    // epilogue for one m-tile
    const int b = mt >> 6, r = mt & 63;
    if (kq < 2) {
      ushort* dstb = kq ? Kb : Qb;
#pragma unroll
      for (int fm = 0; fm < 8; ++fm)
#pragma unroll
        for (int fn = 0; fn < 4; ++fn) {
          int n = n0 + (wn << 6) + (fn << 4) + il;
          int h = (n >> 6) & 7, d = n & 63;
#pragma unroll
          for (int j = 0; j < 4; ++j) {
            int i = (wm << 7) + (fm << 4) + (kl << 2) + j;
            size_t dst = ((size_t)((((b << 3) + h) << 8) + i) << 12) + (r << 6) + d;
            dstb[dst] = f2bf(acc[fm][fn][j]);
          }
        }
    } else {
#pragma unroll
      for (int fm = 0; fm < 8; ++fm)
#pragma unroll
        for (int fn = 0; fn < 4; ++fn) {
          int n = n0 - 1024 + (wn << 6) + (fn << 4) + il;   // h*64+d
          int h = n >> 6, d = n & 63;
          int i0 = (wm << 7) + (fm << 4) + (kl << 2);
          size_t dst = (((size_t)((((b << 3) + h) << 12)) + (r << 6) + d) << 8) + i0;
          ushort4 pk; pk.x = f2bf(acc[fm][fn][0]); pk.y = f2bf(acc[fm][fn][1]);
          pk.z = f2bf(acc[fm][fn][2]); pk.w = f2bf(acc[fm][fn][3]);
          *reinterpret_cast<ushort4*>(&Vt[dst]) = pk;
        }
    }
  };

#pragma unroll
  for (int i = 0; i < 8; ++i)
#pragma unroll
    for (int j = 0; j < 4; ++j) acc[i][j] = f32x4{0.f, 0.f, 0.f, 0.f};

  stageA(lds, 0);         stageB(lds, 0);
  stageA(lds + 24576, 1); stageB(lds + 24576, 1);
  asm volatile("s_waitcnt vmcnt(6)" ::: "memory");
  __builtin_amdgcn_s_barrier();

  int cur = 0, nx = 2;
  const int G = 64;                              // 4 m-tiles x 16 K-tiles
  for (int g = 0; g < G; ++g) {
    if (g > 0 && (g & 15) == 0) {               // tile boundary: flush prev acc
      flush(mtile_of(g - 1));                   // stores precede this iter's
#pragma unroll                                   // stage-issue -> vmcnt ledger
      for (int i = 0; i < 8; ++i)               // still tags 6 newest = loads
#pragma unroll
        for (int j = 0; j < 4; ++j) acc[i][j] = f32x4{0.f, 0.f, 0.f, 0.f};
    }
    char* cbuf = lds + cur * 24576;
    char* sbuf = lds + nx * 24576;
    bf16x8 af[8], bfr[4];
    loadA8(cbuf, af);
    loadB4(cbuf, bfr);
    if (g + 2 < G) { stageA(sbuf, g + 2); stageB(sbuf, g + 2); }
    __builtin_amdgcn_s_setprio(1);
#pragma unroll
    for (int fm = 0; fm < 8; ++fm)
#pragma unroll
      for (int fn = 0; fn < 4; ++fn)
        acc[fm][fn] = MFMA16(af[fm], bfr[fn], acc[fm][fn]);
    __builtin_amdgcn_s_setprio(0);
    if (g + 2 < G) asm volatile("s_waitcnt vmcnt(6)" ::: "memory");
    else           asm volatile("s_waitcnt vmcnt(0)" ::: "memory");
    __builtin_amdgcn_s_barrier();
    cur = (cur == 2) ? 0 : cur + 1;
    nx  = (nx  == 2) ? 0 : nx  + 1;
  }
  flush(mtile_of(G - 1));                       // last tile
}

// ------------------------------- gemm2 (out) --------------------------------
// 512 persistent blocks; 2 m-tiles x 16 K-tiles = 32 flat ring iters.

__global__ __launch_bounds__(256, 2) void gemm_out_k(
    const ushort* __restrict__ O2, const ushort* __restrict__ W0b,
    float* __restrict__ out) {
  __shared__ __align__(16) char lds_s[73728];
  char* lds = lds_s;
  f32x4 acc[8][4];
  const int Bid = blockIdx.x;
  const int xcd = Bid & 7, idx = Bid >> 3;
  const int nt = idx & 3, pg = idx >> 2;        // pg 0..15
  const int n0 = nt << 7;

  const int tid = threadIdx.x, w = tid >> 6, l = tid & 63;
  const int il = l & 15, kl = l >> 4;
  const int wm = w >> 1, wn = w & 1;

  auto mtile_of = [&](int j) { return (((pg << 1) + (j >> 4)) << 3) + xcd; };

  auto stageA = [&](char* buf, int j) {
    const size_t m0j = (size_t)mtile_of(j) << 8;
    const int kt = j & 15;
#pragma unroll
    for (int c = 0; c < 4; ++c) {
      int rbase = (w << 6) + (c << 4);
      int row = rbase + (l >> 2);
      int s = ((l & 3) - ((row >> 1) & 3)) & 3;
      gload_lds16(O2 + (m0j + row) * 512 + (kt << 5) + (s << 3),
                  buf + rbase * 64);
    }
  };
  auto stageB = [&](char* buf, int j) {
    const int kt = j & 15;
#pragma unroll
    for (int c = 0; c < 2; ++c) {
      int rbase = (w << 5) + (c << 4);
      int row = rbase + (l >> 2);
      int s = ((l & 3) - ((row >> 1) & 3)) & 3;
      gload_lds16(W0b + (size_t)(n0 + row) * 512 + (kt << 5) + (s << 3),
                  buf + 16384 + rbase * 64);
    }
  };
  auto loadA8 = [&](const char* buf, bf16x8 (&af)[8]) {
#pragma unroll
    for (int q = 0; q < 8; ++q) {
      int row = (wm << 7) + (q << 4) + il;
      af[q] = *(const bf16x8*)(buf + row * 64 + (((kl + (row >> 1)) & 3) << 4));
    }
  };
  auto loadB4 = [&](const char* buf, bf16x8 (&bfr)[4]) {
#pragma unroll
    for (int q = 0; q < 4; ++q) {
      int row = (wn << 6) + (q << 4) + il;
      bfr[q] = *(const bf16x8*)(buf + 16384 + row * 64 + (((kl + (row >> 1)) & 3) << 4));
    }
  };
  auto flush = [&](int mt) {
    const int mbase = mt << 8;
#pragma unroll
    for (int fm = 0; fm < 8; ++fm)
#pragma unroll
      for (int fn = 0; fn < 4; ++fn) {
        int n = n0 + (wn << 6) + (fn << 4) + il;
#pragma unroll
        for (int j = 0; j < 4; ++j) {
          int m = mbase + (wm << 7) + (fm << 4) + (kl << 2) + j;
          out[(size_t)m * 512 + n] = acc[fm][fn][j];
        }
      }
  };

#pragma unroll
  for (int i = 0; i < 8; ++i)
#pragma unroll
    for (int j = 0; j < 4; ++j) acc[i][j] = f32x4{0.f, 0.f, 0.f, 0.f};

  stageA(lds, 0);         stageB(lds, 0);
  stageA(lds + 24576, 1); stageB(lds + 24576, 1);
  asm volatile("s_waitcnt vmcnt(6)" ::: "memory");
  __builtin_amdgcn_s_barrier();

  int cur = 0, nx = 2;
  const int G = 32;                              // 2 m-tiles x 16 K-tiles
  for (int g = 0; g < G; ++g) {
    if (g > 0 && (g & 15) == 0) {
      flush(mtile_of(g - 1));
#pragma unroll
      for (int i = 0; i < 8; ++i)
#pragma unroll
        for (int j = 0; j < 4; ++j) acc[i][j] = f32x4{0.f, 0.f, 0.f, 0.f};
    }
    char* cbuf = lds + cur * 24576;
    char* sbuf = lds + nx * 24576;
    bf16x8 af[8], bfr[4];
    loadA8(cbuf, af);
    loadB4(cbuf, bfr);
    if (g + 2 < G) { stageA(sbuf, g + 2); stageB(sbuf, g + 2); }
    __builtin_amdgcn_s_setprio(1);
#pragma unroll
    for (int fm = 0; fm < 8; ++fm)
#pragma unroll
      for (int fn = 0; fn < 4; ++fn)
        acc[fm][fn] = MFMA16(af[fm], bfr[fn], acc[fm][fn]);
    __builtin_amdgcn_s_setprio(0);
    if (g + 2 < G) asm volatile("s_waitcnt vmcnt(6)" ::: "memory");
    else           asm volatile("s_waitcnt vmcnt(0)" ::: "memory");
    __builtin_amdgcn_s_barrier();
    cur = (cur == 2) ? 0 : cur + 1;
    nx  = (nx  == 2) ? 0 : nx  + 1;
  }
  flush(mtile_of(G - 1));
}

// ---------------------- gemm_s: S partials (split-K=4) ----------------------
// 256 blocks; Bid = xcd + 8*(j + 8*bhg) so the 8 blocks (4ks x 2nt) of one bh
// are co-XCD (share the 4MB Q+K in that XCD's L2). Spb[z][i][j] BF16.

__global__ __launch_bounds__(256, 2) void gemm_s_k(
    const ushort* __restrict__ Qb, const ushort* __restrict__ Kb,
    ushort* __restrict__ Spb) {
  __shared__ __align__(16) char lds[73728];
  f32x4 acc[8][4];
  const int Bid = blockIdx.x;
  const int xcd = Bid & 7, t = Bid >> 3;        // t 0..31
  const int j8 = t & 7, bh = ((t >> 3) << 3) + xcd;
  const int ks = j8 >> 1, nt = j8 & 1;
  const int z = (bh << 2) + ks;
  const int n0 = nt << 7;
  const size_t base = ((size_t)bh << 20) + ((size_t)ks << 10);
  gemm_nt_256x128(Qb + base, Kb + base, 4096, 4096, 32, 0, n0, lds, acc);

  const int tid = threadIdx.x, w = tid >> 6, l = tid & 63;
  const int il = l & 15, kl = l >> 4;
  const int wm = w >> 1, wn = w & 1;
  ushort* o = Spb + ((size_t)z << 16);
#pragma unroll
  for (int fm = 0; fm < 8; ++fm)
#pragma unroll
    for (int fn = 0; fn < 4; ++fn) {
      int n = n0 + (wn << 6) + (fn << 4) + il;
#pragma unroll
      for (int j = 0; j < 4; ++j) {
        int m = (wm << 7) + (fm << 4) + (kl << 2) + j;
        o[(size_t)m * 256 + n] = f2bf(acc[fm][fn][j]);
      }
    }
}

// ------------------------- softmax (wave per row) ---------------------------
// P[bh][i][j] = softmax_j(sum_{ks=0..3} Spb[4bh+ks] / 64), bf16 with 1/sum.

__global__ void softmax_k(const ushort* __restrict__ Spb, ushort* __restrict__ Pb) {
  const int w = threadIdx.x >> 6, l = threadIdx.x & 63;
  const int row = (blockIdx.x << 2) + w;        // 0..8191
  const int bh = row >> 8, i = row & 255;
  const ushort4* p0 = reinterpret_cast<const ushort4*>(
      Spb + (((size_t)bh << 2) << 16) + ((size_t)i << 8)) + l;
  float s0 = 0.f, s1 = 0.f, s2 = 0.f, s3 = 0.f;
#pragma unroll
  for (int ks = 0; ks < 4; ++ks) {
    ushort4 a = p0[(size_t)ks * 16384];
    s0 += bf2f(a.x); s1 += bf2f(a.y); s2 += bf2f(a.z); s3 += bf2f(a.w);
  }
  const float scale = 0.015625f;
  s0 *= scale; s1 *= scale; s2 *= scale; s3 *= scale;
  float m = fmaxf(fmaxf(s0, s1), fmaxf(s2, s3));
#pragma unroll
  for (int d2 = 1; d2 < 64; d2 <<= 1) m = fmaxf(m, __shfl_xor(m, d2));
  float e0 = __expf(s0 - m), e1 = __expf(s1 - m);
  float e2 = __expf(s2 - m), e3 = __expf(s3 - m);
  float sum = e0 + e1 + e2 + e3;
#pragma unroll
  for (int d2 = 1; d2 < 64; d2 <<= 1) sum += __shfl_xor(sum, d2);
  float r = 1.0f / sum;
  ushort4 p; p.x = f2bf(e0 * r); p.y = f2bf(e1 * r);
  p.z = f2bf(e2 * r); p.w = f2bf(e3 * r);
  reinterpret_cast<ushort4*>(Pb + ((size_t)bh << 16) + ((size_t)i << 8))[l] = p;
}

// ---------------------- gemm_pv: O = P V  (A=Vt, B=P) -----------------------

__global__ __launch_bounds__(256, 2) void gemm_pv_k(
    const ushort* __restrict__ Vt, const ushort* __restrict__ Pb,
    ushort* __restrict__ O2) {
  __shared__ __align__(16) char lds[73728];
  f32x4 acc[8][4];
  const int Bid = blockIdx.x;
  const int xcd = Bid & 7, idx = Bid >> 3;      // idx 0..127
  const int sub = idx & 31, grp = idx >> 5;     // sub: mt*2+nt, grp 0..3
  const int bh = (grp << 3) + xcd, b = bh >> 3, h = bh & 7;
  const int m0 = (sub >> 1) << 8;               // rd tile (16 x 256)
  const int n0 = (sub & 1) << 7;                // i tile (2 x 128)
  gemm_nt_256x128(Vt + ((size_t)bh << 20), Pb + ((size_t)bh << 16),
                  256, 256, 8, m0, n0, lds, acc);

  const int tid = threadIdx.x, w = tid >> 6, l = tid & 63;
  const int il = l & 15, kl = l >> 4;
  const int wm = w >> 1, wn = w & 1;
#pragma unroll
  for (int fm = 0; fm < 8; ++fm) {
    int rd0 = m0 + (wm << 7) + (fm << 4) + (kl << 2);
    int r = rd0 >> 6, d0 = rd0 & 63;
#pragma unroll
    for (int fn = 0; fn < 4; ++fn) {
      int i = n0 + (wn << 6) + (fn << 4) + il;
      ushort4 pk; pk.x = f2bf(acc[fm][fn][0]); pk.y = f2bf(acc[fm][fn][1]);
      pk.z = f2bf(acc[fm][fn][2]); pk.w = f2bf(acc[fm][fn][3]);
      *reinterpret_cast<ushort4*>(
          O2 + ((size_t)((((b << 6) + r) << 8) + i) << 9) + (h << 6) + d0) = pk;
    }
  }
}

// ------------------------------- launcher -----------------------------------

extern "C" void kernel_launch(void* const* d_in, const int* in_sizes, int n_in,
                              void* d_out, int out_size, void* d_ws, size_t ws_size,
                              hipStream_t stream) {
  const float* x    = (const float*)d_in[0];
  const float* Wqkv = (const float*)d_in[1];
  const float* W0   = (const float*)d_in[2];
  float* out = (float*)d_out;

  char* ws = (char*)d_ws;
  ushort* xb  = (ushort*)(ws);                    // 67,108,864 B (-> Spb -> O2)
  ushort* Wp  = (ushort*)(ws + 67108864);         //  1,572,864
  ushort* W0b = (ushort*)(ws + 68681728);         //    524,288
  ushort* Qb  = (ushort*)(ws + 69206016);         // 67,108,864 (-> Pb)
  ushort* Kb  = (ushort*)(ws + 136314880);        // 67,108,864
  ushort* Vt  = (ushort*)(ws + 203423744);        // 67,108,864  -> total 270,532,608
  if (ws_size < 270532608ull) return;             // workspace too small: fail visibly

  cast_f32_to_bf16<<<2048, 256, 0, stream>>>(x, xb, 8388608);
  prep_k<<<832, 256, 0, stream>>>(Wqkv, Wp, W0, W0b);

  gemm_qkv_k<<<768, 256, 0, stream>>>(xb, Wp, Qb, Kb, Vt);

  ushort* Spb = xb;                               // xb dead after gemm1 (16.8 MB)
  ushort* Pb  = Qb;                               // Qb dead after gemm_s (4.2 MB)
  ushort* O2  = xb;                               // Spb dead after softmax (64 MB)

  gemm_s_k<<<256, 256, 0, stream>>>(Qb, Kb, Spb);
  softmax_k<<<2048, 256, 0, stream>>>(Spb, Pb);
  gemm_pv_k<<<1024, 256, 0, stream>>>(Vt, Pb, O2);

  gemm_out_k<<<512, 256, 0, stream>>>(O2, W0b, out);
}

// Round 14
// 289.295 us; speedup vs baseline: 1.8257x; 1.8257x over previous
//
#include <hip/hip_runtime.h>

// ---------------------------------------------------------------------------
// TiedRowAxialAttention on MI355X (gfx950), bf16 MFMA pipeline.
// dims: b=4 rows=64 t=256 dim=512 heads=8 dim_head=64 ; scale = 1/64
// stages:
//   prep:   x->bf16 (xb) + W_qkv permute/cast + W0 cast  (ONE dispatch)
//   gemm1:  qkv = xb @ Wp^T -> Q[bh][i][rd], K[bh][j][rd], Vt[bh][rd][j]
//           (R7-proven form: single m-tile per block, epilogue after loop)
//   gemm_s: S[bh][i][j] partials (split-K=4) -> BF16 (halved traffic),
//           XCD-grouped so one bh's 8 blocks share an XCD L2.
//   softmax: wave-per-row over 4 bf16 partials, P = softmax(S/64) bf16.
//   gemm_pv: O = P V via A=Vt,B=P -> O2[(b,r,i)][hd]
//   gemm2:  out = O2 @ W0^T -> fp32 (R7 form)
// GEMM mainloop: 256x128 tile, BK=32, 4 waves (2Mx2N, per-wave 128x64,
// acc[8][4]), 3 LDS buffers (72 KB, 2 blk/CU), 2-tile prefetch lead,
// counted vmcnt(6) (never 0 mid-loop; NO global stores inside the loop —
// R12 lesson: stores poison the counted-vmcnt ledger), 1 barrier/K-tile.
// ---------------------------------------------------------------------------

typedef short  bf16x8 __attribute__((ext_vector_type(8)));
typedef float  f32x4  __attribute__((ext_vector_type(4)));

#define MFMA16(a,b,c) __builtin_amdgcn_mfma_f32_16x16x32_bf16((a),(b),(c),0,0,0)

__device__ __forceinline__ ushort f2bf(float f) {
  union { float f; unsigned u; } v; v.f = f;
  unsigned r = v.u + 0x7fffu + ((v.u >> 16) & 1u);   // RNE
  return (ushort)(r >> 16);
}

__device__ __forceinline__ float bf2f(ushort u) {
  union { unsigned u; float f; } v; v.u = ((unsigned)u) << 16;
  return v.f;
}

__device__ __forceinline__ void gload_lds16(const void* g, void* lds) {
  __builtin_amdgcn_global_load_lds(
      (const __attribute__((address_space(1))) void*)g,
      (__attribute__((address_space(3))) void*)lds, 16, 0, 0);
}

// -------------------------------- prep (one dispatch) -----------------------
// blocks 0..2047: cast x (4096 float4 each); 2048..2815: permute W_qkv;
// 2816..2879: cast W0.

__global__ void prep_all_k(const float* __restrict__ x, ushort* __restrict__ xb,
                           const float* __restrict__ W, ushort* __restrict__ Wp,
                           const float* __restrict__ W0, ushort* __restrict__ W0b) {
  const int bid = blockIdx.x, tid = threadIdx.x;
  if (bid < 2048) {
    int v0 = (bid << 12) + tid;                 // 4096 f4 per block, stride 256
#pragma unroll
    for (int q = 0; q < 16; ++q) {
      int v = v0 + (q << 8);
      float4 f = reinterpret_cast<const float4*>(x)[v];
      ushort4 u; u.x = f2bf(f.x); u.y = f2bf(f.y); u.z = f2bf(f.z); u.w = f2bf(f.w);
      reinterpret_cast<ushort4*>(xb)[v] = u;
    }
  } else if (bid < 2816) {
    int np = ((bid - 2048) << 1) + (tid >> 7);  // 0..1535
    int c  = tid & 127;
    int k = np >> 9, h = (np >> 6) & 7, d = np & 63;
    float4 f = reinterpret_cast<const float4*>(
        W + (size_t)(d * 24 + k * 8 + h) * 512)[c];
    ushort4 u; u.x = f2bf(f.x); u.y = f2bf(f.y); u.z = f2bf(f.z); u.w = f2bf(f.w);
    reinterpret_cast<ushort4*>(Wp + (size_t)np * 512)[c] = u;
  } else {
    int v0 = ((bid - 2816) << 10) + (tid << 2); // 64 blocks x 1024 f4
#pragma unroll
    for (int q = 0; q < 4; ++q) {
      int v = v0 + q;
      float4 f = reinterpret_cast<const float4*>(W0)[v];
      ushort4 u; u.x = f2bf(f.x); u.y = f2bf(f.y); u.z = f2bf(f.z); u.w = f2bf(f.w);
      reinterpret_cast<ushort4*>(W0b)[v] = u;
    }
  }
}

// ================== 256x128 pipelined NT mainloop (4 waves) =================
// C = A @ B^T ; A [M][lda], B [N][ldb] bf16 row-major, K = 32*P.
// 256 threads = 4 waves (2M x 2N), per-wave 128x64 out = acc[8][4].
// 3 LDS buffers (24KB each), 2-tile lead, vmcnt(6) per K-tile, 1 barrier/tile.
// LDS per-row slot rotation: slot t at row r holds k-slot (t - r>>1)&3.

__device__ __forceinline__ void gemm_nt_256x128(
    const ushort* __restrict__ A, const ushort* __restrict__ B,
    int lda, int ldb, int P, int m0, int n0, char* lds, f32x4 (&acc)[8][4]) {
  const int tid = threadIdx.x;
  const int w = tid >> 6, l = tid & 63;
  const int il = l & 15, kl = l >> 4;
  const int wm = w >> 1, wn = w & 1;

  auto stageA = [&](char* buf, int kt) {
#pragma unroll
    for (int c = 0; c < 4; ++c) {
      int rbase = (w << 6) + (c << 4);                     // wave-uniform
      int row = rbase + (l >> 2);
      int s = ((l & 3) - ((row >> 1) & 3)) & 3;
      gload_lds16(A + (size_t)(m0 + row) * lda + (kt << 5) + (s << 3),
                  buf + rbase * 64);
    }
  };
  auto stageB = [&](char* buf, int kt) {
#pragma unroll
    for (int c = 0; c < 2; ++c) {
      int rbase = (w << 5) + (c << 4);                     // wave-uniform
      int row = rbase + (l >> 2);
      int s = ((l & 3) - ((row >> 1) & 3)) & 3;
      gload_lds16(B + (size_t)(n0 + row) * ldb + (kt << 5) + (s << 3),
                  buf + 16384 + rbase * 64);
    }
  };
  auto loadA8 = [&](const char* buf, bf16x8 (&af)[8]) {
#pragma unroll
    for (int q = 0; q < 8; ++q) {
      int row = (wm << 7) + (q << 4) + il;
      af[q] = *(const bf16x8*)(buf + row * 64 + (((kl + (row >> 1)) & 3) << 4));
    }
  };
  auto loadB4 = [&](const char* buf, bf16x8 (&bfr)[4]) {
#pragma unroll
    for (int q = 0; q < 4; ++q) {
      int row = (wn << 6) + (q << 4) + il;
      bfr[q] = *(const bf16x8*)(buf + 16384 + row * 64 + (((kl + (row >> 1)) & 3) << 4));
    }
  };

#pragma unroll
  for (int i = 0; i < 8; ++i)
#pragma unroll
    for (int j = 0; j < 4; ++j) acc[i][j] = f32x4{0.f, 0.f, 0.f, 0.f};

  stageA(lds, 0);         stageB(lds, 0);
  stageA(lds + 24576, 1); stageB(lds + 24576, 1);
  asm volatile("s_waitcnt vmcnt(6)" ::: "memory");
  __builtin_amdgcn_s_barrier();

  int cur = 0, nx = 2;
  for (int g = 0; g < P; ++g) {
    char* cbuf = lds + cur * 24576;
    char* sbuf = lds + nx * 24576;
    bf16x8 af[8], bfr[4];
    loadA8(cbuf, af);
    loadB4(cbuf, bfr);
    if (g + 2 < P) { stageA(sbuf, g + 2); stageB(sbuf, g + 2); }
    __builtin_amdgcn_s_setprio(1);
#pragma unroll
    for (int fm = 0; fm < 8; ++fm)
#pragma unroll
      for (int fn = 0; fn < 4; ++fn)
        acc[fm][fn] = MFMA16(af[fm], bfr[fn], acc[fm][fn]);
    __builtin_amdgcn_s_setprio(0);
    if (g + 2 < P) asm volatile("s_waitcnt vmcnt(6)" ::: "memory");
    else           asm volatile("s_waitcnt vmcnt(0)" ::: "memory");
    __builtin_amdgcn_s_barrier();
    cur = (cur == 2) ? 0 : cur + 1;
    nx  = (nx  == 2) ? 0 : nx  + 1;
  }
}

// ------------------------------- gemm1 (qkv) --------------------------------
// 3072 blocks; XCD swizzle. R7-proven form.

__global__ __launch_bounds__(256, 2) void gemm_qkv_k(
    const ushort* __restrict__ xb, const ushort* __restrict__ Wp,
    ushort* __restrict__ Qb, ushort* __restrict__ Kb, ushort* __restrict__ Vt) {
  __shared__ __align__(16) char lds[73728];
  f32x4 acc[8][4];
  const int Bid = blockIdx.x;
  const int xcd = Bid & 7, idx = Bid >> 3;
  const int nt = idx % 12, pl = idx / 12;       // pl 0..31
  const int m0 = ((pl << 3) + xcd) << 8;        // 256 m-tiles * 256
  const int n0 = nt << 7;
  gemm_nt_256x128(xb, Wp, 512, 512, 16, m0, n0, lds, acc);

  const int tid = threadIdx.x, w = tid >> 6, l = tid & 63;
  const int il = l & 15, kl = l >> 4;
  const int wm = w >> 1, wn = w & 1;
  const int kq = n0 >> 9;                       // block-uniform: 0=Q 1=K 2=V
  const int br = m0 >> 8, b = br >> 6, r = br & 63;   // one (b,r) per block

  if (kq < 2) {
    ushort* dstb = kq ? Kb : Qb;
#pragma unroll
    for (int fm = 0; fm < 8; ++fm)
#pragma unroll
      for (int fn = 0; fn < 4; ++fn) {
        int n = n0 + (wn << 6) + (fn << 4) + il;
        int h = (n >> 6) & 7, d = n & 63;
#pragma unroll
        for (int j = 0; j < 4; ++j) {
          int i = (wm << 7) + (fm << 4) + (kl << 2) + j;
          size_t dst = ((size_t)((((b << 3) + h) << 8) + i) << 12) + (r << 6) + d;
          dstb[dst] = f2bf(acc[fm][fn][j]);     // lanes: 2B x16 contiguous in d
        }
      }
  } else {
#pragma unroll
    for (int fm = 0; fm < 8; ++fm)
#pragma unroll
      for (int fn = 0; fn < 4; ++fn) {
        int n = n0 - 1024 + (wn << 6) + (fn << 4) + il;     // h*64+d
        int h = n >> 6, d = n & 63;
        int i0 = (wm << 7) + (fm << 4) + (kl << 2);
        size_t dst = (((size_t)((((b << 3) + h) << 12)) + (r << 6) + d) << 8) + i0;
        ushort4 pk; pk.x = f2bf(acc[fm][fn][0]); pk.y = f2bf(acc[fm][fn][1]);
        pk.z = f2bf(acc[fm][fn][2]); pk.w = f2bf(acc[fm][fn][3]);
        *reinterpret_cast<ushort4*>(&Vt[dst]) = pk;   // 4 consecutive i
      }
  }
}

// ------------------------------- gemm2 (out) --------------------------------
// 1024 blocks; XCD swizzle; scalar f32 stores (lanes 4B x16 contiguous).

__global__ __launch_bounds__(256, 2) void gemm_out_k(
    const ushort* __restrict__ O2, const ushort* __restrict__ W0b,
    float* __restrict__ out) {
  __shared__ __align__(16) char lds[73728];
  f32x4 acc[8][4];
  const int Bid = blockIdx.x;
  const int xcd = Bid & 7, idx = Bid >> 3;
  const int nt = idx & 3, pl = idx >> 2;        // pl 0..31
  const int m0 = ((pl << 3) + xcd) << 8;
  const int n0 = nt << 7;
  gemm_nt_256x128(O2, W0b, 512, 512, 16, m0, n0, lds, acc);

  const int tid = threadIdx.x, w = tid >> 6, l = tid & 63;
  const int il = l & 15, kl = l >> 4;
  const int wm = w >> 1, wn = w & 1;
#pragma unroll
  for (int fm = 0; fm < 8; ++fm)
#pragma unroll
    for (int fn = 0; fn < 4; ++fn) {
      int n = n0 + (wn << 6) + (fn << 4) + il;
#pragma unroll
      for (int j = 0; j < 4; ++j) {
        int m = m0 + (wm << 7) + (fm << 4) + (kl << 2) + j;
        out[(size_t)m * 512 + n] = acc[fm][fn][j];
      }
    }
}

// ---------------------- gemm_s: S partials (split-K=4) ----------------------
// 256 blocks; Bid = xcd + 8*(j8 + 8*bhg) so the 8 blocks (4ks x 2nt) of one
// bh are co-XCD (share the 4MB Q+K in that XCD's L2). Spb[z][i][j] BF16.

__global__ __launch_bounds__(256, 2) void gemm_s_k(
    const ushort* __restrict__ Qb, const ushort* __restrict__ Kb,
    ushort* __restrict__ Spb) {
  __shared__ __align__(16) char lds[73728];
  f32x4 acc[8][4];
  const int Bid = blockIdx.x;
  const int xcd = Bid & 7, t = Bid >> 3;        // t 0..31
  const int j8 = t & 7, bh = ((t >> 3) << 3) + xcd;
  const int ks = j8 >> 1, nt = j8 & 1;
  const int z = (bh << 2) + ks;
  const int n0 = nt << 7;
  const size_t base = ((size_t)bh << 20) + ((size_t)ks << 10);
  gemm_nt_256x128(Qb + base, Kb + base, 4096, 4096, 32, 0, n0, lds, acc);

  const int tid = threadIdx.x, w = tid >> 6, l = tid & 63;
  const int il = l & 15, kl = l >> 4;
  const int wm = w >> 1, wn = w & 1;
  ushort* o = Spb + ((size_t)z << 16);
#pragma unroll
  for (int fm = 0; fm < 8; ++fm)
#pragma unroll
    for (int fn = 0; fn < 4; ++fn) {
      int n = n0 + (wn << 6) + (fn << 4) + il;
#pragma unroll
      for (int j = 0; j < 4; ++j) {
        int m = (wm << 7) + (fm << 4) + (kl << 2) + j;
        o[(size_t)m * 256 + n] = f2bf(acc[fm][fn][j]);
      }
    }
}

// ------------------------- softmax (wave per row) ---------------------------
// P[bh][i][j] = softmax_j(sum_{ks=0..3} Spb[4bh+ks] / 64), bf16 with 1/sum.

__global__ void softmax_k(const ushort* __restrict__ Spb, ushort* __restrict__ Pb) {
  const int w = threadIdx.x >> 6, l = threadIdx.x & 63;
  const int row = (blockIdx.x << 2) + w;        // 0..8191
  const int bh = row >> 8, i = row & 255;
  const ushort4* p0 = reinterpret_cast<const ushort4*>(
      Spb + (((size_t)bh << 2) << 16) + ((size_t)i << 8)) + l;
  float s0 = 0.f, s1 = 0.f, s2 = 0.f, s3 = 0.f;
#pragma unroll
  for (int ks = 0; ks < 4; ++ks) {
    ushort4 a = p0[(size_t)ks * 16384];
    s0 += bf2f(a.x); s1 += bf2f(a.y); s2 += bf2f(a.z); s3 += bf2f(a.w);
  }
  const float scale = 0.015625f;
  s0 *= scale; s1 *= scale; s2 *= scale; s3 *= scale;
  float m = fmaxf(fmaxf(s0, s1), fmaxf(s2, s3));
#pragma unroll
  for (int d2 = 1; d2 < 64; d2 <<= 1) m = fmaxf(m, __shfl_xor(m, d2));
  float e0 = __expf(s0 - m), e1 = __expf(s1 - m);
  float e2 = __expf(s2 - m), e3 = __expf(s3 - m);
  float sum = e0 + e1 + e2 + e3;
#pragma unroll
  for (int d2 = 1; d2 < 64; d2 <<= 1) sum += __shfl_xor(sum, d2);
  float r = 1.0f / sum;
  ushort4 p; p.x = f2bf(e0 * r); p.y = f2bf(e1 * r);
  p.z = f2bf(e2 * r); p.w = f2bf(e3 * r);
  reinterpret_cast<ushort4*>(Pb + ((size_t)bh << 16) + ((size_t)i << 8))[l] = p;
}

// ---------------------- gemm_pv: O = P V  (A=Vt, B=P) -----------------------
// 1024 blocks; XCD swizzle groups one bh's 32 blocks on one XCD.

__global__ __launch_bounds__(256, 2) void gemm_pv_k(
    const ushort* __restrict__ Vt, const ushort* __restrict__ Pb,
    ushort* __restrict__ O2) {
  __shared__ __align__(16) char lds[73728];
  f32x4 acc[8][4];
  const int Bid = blockIdx.x;
  const int xcd = Bid & 7, idx = Bid >> 3;      // idx 0..127
  const int sub = idx & 31, grp = idx >> 5;     // sub: mt*2+nt, grp 0..3
  const int bh = (grp << 3) + xcd, b = bh >> 3, h = bh & 7;
  const int m0 = (sub >> 1) << 8;               // rd tile (16 x 256)
  const int n0 = (sub & 1) << 7;                // i tile (2 x 128)
  gemm_nt_256x128(Vt + ((size_t)bh << 20), Pb + ((size_t)bh << 16),
                  256, 256, 8, m0, n0, lds, acc);

  const int tid = threadIdx.x, w = tid >> 6, l = tid & 63;
  const int il = l & 15, kl = l >> 4;
  const int wm = w >> 1, wn = w & 1;
#pragma unroll
  for (int fm = 0; fm < 8; ++fm) {
    int rd0 = m0 + (wm << 7) + (fm << 4) + (kl << 2);
    int r = rd0 >> 6, d0 = rd0 & 63;
#pragma unroll
    for (int fn = 0; fn < 4; ++fn) {
      int i = n0 + (wn << 6) + (fn << 4) + il;
      ushort4 pk; pk.x = f2bf(acc[fm][fn][0]); pk.y = f2bf(acc[fm][fn][1]);
      pk.z = f2bf(acc[fm][fn][2]); pk.w = f2bf(acc[fm][fn][3]);
      *reinterpret_cast<ushort4*>(
          O2 + ((size_t)((((b << 6) + r) << 8) + i) << 9) + (h << 6) + d0) = pk;
    }
  }
}

// ------------------------------- launcher -----------------------------------

extern "C" void kernel_launch(void* const* d_in, const int* in_sizes, int n_in,
                              void* d_out, int out_size, void* d_ws, size_t ws_size,
                              hipStream_t stream) {
  const float* x    = (const float*)d_in[0];
  const float* Wqkv = (const float*)d_in[1];
  const float* W0   = (const float*)d_in[2];
  float* out = (float*)d_out;

  char* ws = (char*)d_ws;
  ushort* xb  = (ushort*)(ws);                    // 67,108,864 B (-> Spb -> O2)
  ushort* Wp  = (ushort*)(ws + 67108864);         //  1,572,864
  ushort* W0b = (ushort*)(ws + 68681728);         //    524,288
  ushort* Qb  = (ushort*)(ws + 69206016);         // 67,108,864 (-> Pb)
  ushort* Kb  = (ushort*)(ws + 136314880);        // 67,108,864
  ushort* Vt  = (ushort*)(ws + 203423744);        // 67,108,864  -> total 270,532,608
  if (ws_size < 270532608ull) return;             // workspace too small: fail visibly

  prep_all_k<<<2880, 256, 0, stream>>>(x, xb, Wqkv, Wp, W0, W0b);

  gemm_qkv_k<<<3072, 256, 0, stream>>>(xb, Wp, Qb, Kb, Vt);

  ushort* Spb = xb;                               // xb dead after gemm1 (16.8 MB)
  ushort* Pb  = Qb;                               // Qb dead after gemm_s (4.2 MB)
  ushort* O2  = xb;                               // Spb dead after softmax (64 MB)

  gemm_s_k<<<256, 256, 0, stream>>>(Qb, Kb, Spb);
  softmax_k<<<2048, 256, 0, stream>>>(Spb, Pb);
  gemm_pv_k<<<1024, 256, 0, stream>>>(Vt, Pb, O2);

  gemm_out_k<<<1024, 256, 0, stream>>>(O2, W0b, out);
}

// Round 15
// 289.168 us; speedup vs baseline: 1.8265x; 1.0004x over previous
//
#include <hip/hip_runtime.h>

// ---------------------------------------------------------------------------
// TiedRowAxialAttention on MI355X (gfx950), bf16 MFMA pipeline.
// dims: b=4 rows=64 t=256 dim=512 heads=8 dim_head=64 ; scale = 1/64
// stages:
//   prep:   x->bf16 (xb) + W_qkv permute/cast + W0 cast  (ONE dispatch)
//   gemm1:  qkv = xb @ Wp^T -> Q[bh][i][rd], K[bh][j][rd], Vt[bh][rd][j]
//   gemm_s: S partials (split-K=8 -> 512 blocks, 2 blk/CU) -> BF16,
//           XCD-grouped so one bh's 16 blocks share an XCD L2.
//   softmax: wave-per-row over 8 bf16 partials, P = softmax(S/64) bf16.
//   gemm_pv: O = P V via A=Vt,B=P -> O2[(b,r,i)][hd]
//   gemm2:  out = O2 @ W0^T -> fp32
// GEMM mainloop: 256x128 tile, BK=32, 4 waves (2Mx2N, per-wave 128x64,
// acc[8][4]), 3 LDS buffers (72 KB, 2 blk/CU), 2-tile prefetch lead,
// counted vmcnt(6) (never 0 mid-loop; NO global stores inside the loop —
// R12 lesson: stores poison the counted-vmcnt ledger), 1 barrier/K-tile.
// gemm_qkv = 805 TF = m97-structure ceiling at K=512 (6 variants confirmed).
// ---------------------------------------------------------------------------

typedef short  bf16x8 __attribute__((ext_vector_type(8)));
typedef float  f32x4  __attribute__((ext_vector_type(4)));

#define MFMA16(a,b,c) __builtin_amdgcn_mfma_f32_16x16x32_bf16((a),(b),(c),0,0,0)

__device__ __forceinline__ ushort f2bf(float f) {
  union { float f; unsigned u; } v; v.f = f;
  unsigned r = v.u + 0x7fffu + ((v.u >> 16) & 1u);   // RNE
  return (ushort)(r >> 16);
}

__device__ __forceinline__ float bf2f(ushort u) {
  union { unsigned u; float f; } v; v.u = ((unsigned)u) << 16;
  return v.f;
}

__device__ __forceinline__ void gload_lds16(const void* g, void* lds) {
  __builtin_amdgcn_global_load_lds(
      (const __attribute__((address_space(1))) void*)g,
      (__attribute__((address_space(3))) void*)lds, 16, 0, 0);
}

// -------------------------------- prep (one dispatch) -----------------------
// blocks 0..2047: cast x (4096 float4 each); 2048..2815: permute W_qkv;
// 2816..2879: cast W0.

__global__ void prep_all_k(const float* __restrict__ x, ushort* __restrict__ xb,
                           const float* __restrict__ W, ushort* __restrict__ Wp,
                           const float* __restrict__ W0, ushort* __restrict__ W0b) {
  const int bid = blockIdx.x, tid = threadIdx.x;
  if (bid < 2048) {
    int v0 = (bid << 12) + tid;                 // 4096 f4 per block, stride 256
#pragma unroll
    for (int q = 0; q < 16; ++q) {
      int v = v0 + (q << 8);
      float4 f = reinterpret_cast<const float4*>(x)[v];
      ushort4 u; u.x = f2bf(f.x); u.y = f2bf(f.y); u.z = f2bf(f.z); u.w = f2bf(f.w);
      reinterpret_cast<ushort4*>(xb)[v] = u;
    }
  } else if (bid < 2816) {
    int np = ((bid - 2048) << 1) + (tid >> 7);  // 0..1535
    int c  = tid & 127;
    int k = np >> 9, h = (np >> 6) & 7, d = np & 63;
    float4 f = reinterpret_cast<const float4*>(
        W + (size_t)(d * 24 + k * 8 + h) * 512)[c];
    ushort4 u; u.x = f2bf(f.x); u.y = f2bf(f.y); u.z = f2bf(f.z); u.w = f2bf(f.w);
    reinterpret_cast<ushort4*>(Wp + (size_t)np * 512)[c] = u;
  } else {
    int v0 = ((bid - 2816) << 10) + (tid << 2); // 64 blocks x 1024 f4
#pragma unroll
    for (int q = 0; q < 4; ++q) {
      int v = v0 + q;
      float4 f = reinterpret_cast<const float4*>(W0)[v];
      ushort4 u; u.x = f2bf(f.x); u.y = f2bf(f.y); u.z = f2bf(f.z); u.w = f2bf(f.w);
      reinterpret_cast<ushort4*>(W0b)[v] = u;
    }
  }
}

// ================== 256x128 pipelined NT mainloop (4 waves) =================
// C = A @ B^T ; A [M][lda], B [N][ldb] bf16 row-major, K = 32*P.
// 256 threads = 4 waves (2M x 2N), per-wave 128x64 out = acc[8][4].
// 3 LDS buffers (24KB each), 2-tile lead, vmcnt(6) per K-tile, 1 barrier/tile.
// LDS per-row slot rotation: slot t at row r holds k-slot (t - r>>1)&3.

__device__ __forceinline__ void gemm_nt_256x128(
    const ushort* __restrict__ A, const ushort* __restrict__ B,
    int lda, int ldb, int P, int m0, int n0, char* lds, f32x4 (&acc)[8][4]) {
  const int tid = threadIdx.x;
  const int w = tid >> 6, l = tid & 63;
  const int il = l & 15, kl = l >> 4;
  const int wm = w >> 1, wn = w & 1;

  auto stageA = [&](char* buf, int kt) {
#pragma unroll
    for (int c = 0; c < 4; ++c) {
      int rbase = (w << 6) + (c << 4);                     // wave-uniform
      int row = rbase + (l >> 2);
      int s = ((l & 3) - ((row >> 1) & 3)) & 3;
      gload_lds16(A + (size_t)(m0 + row) * lda + (kt << 5) + (s << 3),
                  buf + rbase * 64);
    }
  };
  auto stageB = [&](char* buf, int kt) {
#pragma unroll
    for (int c = 0; c < 2; ++c) {
      int rbase = (w << 5) + (c << 4);                     // wave-uniform
      int row = rbase + (l >> 2);
      int s = ((l & 3) - ((row >> 1) & 3)) & 3;
      gload_lds16(B + (size_t)(n0 + row) * ldb + (kt << 5) + (s << 3),
                  buf + 16384 + rbase * 64);
    }
  };
  auto loadA8 = [&](const char* buf, bf16x8 (&af)[8]) {
#pragma unroll
    for (int q = 0; q < 8; ++q) {
      int row = (wm << 7) + (q << 4) + il;
      af[q] = *(const bf16x8*)(buf + row * 64 + (((kl + (row >> 1)) & 3) << 4));
    }
  };
  auto loadB4 = [&](const char* buf, bf16x8 (&bfr)[4]) {
#pragma unroll
    for (int q = 0; q < 4; ++q) {
      int row = (wn << 6) + (q << 4) + il;
      bfr[q] = *(const bf16x8*)(buf + 16384 + row * 64 + (((kl + (row >> 1)) & 3) << 4));
    }
  };

#pragma unroll
  for (int i = 0; i < 8; ++i)
#pragma unroll
    for (int j = 0; j < 4; ++j) acc[i][j] = f32x4{0.f, 0.f, 0.f, 0.f};

  stageA(lds, 0);         stageB(lds, 0);
  stageA(lds + 24576, 1); stageB(lds + 24576, 1);
  asm volatile("s_waitcnt vmcnt(6)" ::: "memory");
  __builtin_amdgcn_s_barrier();

  int cur = 0, nx = 2;
  for (int g = 0; g < P; ++g) {
    char* cbuf = lds + cur * 24576;
    char* sbuf = lds + nx * 24576;
    bf16x8 af[8], bfr[4];
    loadA8(cbuf, af);
    loadB4(cbuf, bfr);
    if (g + 2 < P) { stageA(sbuf, g + 2); stageB(sbuf, g + 2); }
    __builtin_amdgcn_s_setprio(1);
#pragma unroll
    for (int fm = 0; fm < 8; ++fm)
#pragma unroll
      for (int fn = 0; fn < 4; ++fn)
        acc[fm][fn] = MFMA16(af[fm], bfr[fn], acc[fm][fn]);
    __builtin_amdgcn_s_setprio(0);
    if (g + 2 < P) asm volatile("s_waitcnt vmcnt(6)" ::: "memory");
    else           asm volatile("s_waitcnt vmcnt(0)" ::: "memory");
    __builtin_amdgcn_s_barrier();
    cur = (cur == 2) ? 0 : cur + 1;
    nx  = (nx  == 2) ? 0 : nx  + 1;
  }
}

// ------------------------------- gemm1 (qkv) --------------------------------
// 3072 blocks; XCD swizzle. R7-proven form.

__global__ __launch_bounds__(256, 2) void gemm_qkv_k(
    const ushort* __restrict__ xb, const ushort* __restrict__ Wp,
    ushort* __restrict__ Qb, ushort* __restrict__ Kb, ushort* __restrict__ Vt) {
  __shared__ __align__(16) char lds[73728];
  f32x4 acc[8][4];
  const int Bid = blockIdx.x;
  const int xcd = Bid & 7, idx = Bid >> 3;
  const int nt = idx % 12, pl = idx / 12;       // pl 0..31
  const int m0 = ((pl << 3) + xcd) << 8;        // 256 m-tiles * 256
  const int n0 = nt << 7;
  gemm_nt_256x128(xb, Wp, 512, 512, 16, m0, n0, lds, acc);

  const int tid = threadIdx.x, w = tid >> 6, l = tid & 63;
  const int il = l & 15, kl = l >> 4;
  const int wm = w >> 1, wn = w & 1;
  const int kq = n0 >> 9;                       // block-uniform: 0=Q 1=K 2=V
  const int br = m0 >> 8, b = br >> 6, r = br & 63;   // one (b,r) per block

  if (kq < 2) {
    ushort* dstb = kq ? Kb : Qb;
#pragma unroll
    for (int fm = 0; fm < 8; ++fm)
#pragma unroll
      for (int fn = 0; fn < 4; ++fn) {
        int n = n0 + (wn << 6) + (fn << 4) + il;
        int h = (n >> 6) & 7, d = n & 63;
#pragma unroll
        for (int j = 0; j < 4; ++j) {
          int i = (wm << 7) + (fm << 4) + (kl << 2) + j;
          size_t dst = ((size_t)((((b << 3) + h) << 8) + i) << 12) + (r << 6) + d;
          dstb[dst] = f2bf(acc[fm][fn][j]);     // lanes: 2B x16 contiguous in d
        }
      }
  } else {
#pragma unroll
    for (int fm = 0; fm < 8; ++fm)
#pragma unroll
      for (int fn = 0; fn < 4; ++fn) {
        int n = n0 - 1024 + (wn << 6) + (fn << 4) + il;     // h*64+d
        int h = n >> 6, d = n & 63;
        int i0 = (wm << 7) + (fm << 4) + (kl << 2);
        size_t dst = (((size_t)((((b << 3) + h) << 12)) + (r << 6) + d) << 8) + i0;
        ushort4 pk; pk.x = f2bf(acc[fm][fn][0]); pk.y = f2bf(acc[fm][fn][1]);
        pk.z = f2bf(acc[fm][fn][2]); pk.w = f2bf(acc[fm][fn][3]);
        *reinterpret_cast<ushort4*>(&Vt[dst]) = pk;   // 4 consecutive i
      }
  }
}

// ------------------------------- gemm2 (out) --------------------------------
// 1024 blocks; XCD swizzle; scalar f32 stores (lanes 4B x16 contiguous).

__global__ __launch_bounds__(256, 2) void gemm_out_k(
    const ushort* __restrict__ O2, const ushort* __restrict__ W0b,
    float* __restrict__ out) {
  __shared__ __align__(16) char lds[73728];
  f32x4 acc[8][4];
  const int Bid = blockIdx.x;
  const int xcd = Bid & 7, idx = Bid >> 3;
  const int nt = idx & 3, pl = idx >> 2;        // pl 0..31
  const int m0 = ((pl << 3) + xcd) << 8;
  const int n0 = nt << 7;
  gemm_nt_256x128(O2, W0b, 512, 512, 16, m0, n0, lds, acc);

  const int tid = threadIdx.x, w = tid >> 6, l = tid & 63;
  const int il = l & 15, kl = l >> 4;
  const int wm = w >> 1, wn = w & 1;
#pragma unroll
  for (int fm = 0; fm < 8; ++fm)
#pragma unroll
    for (int fn = 0; fn < 4; ++fn) {
      int n = n0 + (wn << 6) + (fn << 4) + il;
#pragma unroll
      for (int j = 0; j < 4; ++j) {
        int m = m0 + (wm << 7) + (fm << 4) + (kl << 2) + j;
        out[(size_t)m * 512 + n] = acc[fm][fn][j];
      }
    }
}

// ---------------------- gemm_s: S partials (split-K=8) ----------------------
// 512 blocks (2 blk/CU); Bid = xcd + 8*(j16 + 16*bhg) so one bh's 16 blocks
// (8ks x 2nt) are co-XCD (share the 4MB Q+K in that XCD's L2).
// Each block: 256x128 slab over rd-range ks*512..+512 (P=16). Spb[z] BF16.

__global__ __launch_bounds__(256, 2) void gemm_s_k(
    const ushort* __restrict__ Qb, const ushort* __restrict__ Kb,
    ushort* __restrict__ Spb) {
  __shared__ __align__(16) char lds[73728];
  f32x4 acc[8][4];
  const int Bid = blockIdx.x;
  const int xcd = Bid & 7, t = Bid >> 3;        // t 0..63
  const int j16 = t & 15, bh = ((t >> 4) << 3) + xcd;
  const int ks = j16 >> 1, nt = j16 & 1;
  const int z = (bh << 3) + ks;                 // 0..255
  const int n0 = nt << 7;
  const size_t base = ((size_t)bh << 20) + ((size_t)ks << 9);
  gemm_nt_256x128(Qb + base, Kb + base, 4096, 4096, 16, 0, n0, lds, acc);

  const int tid = threadIdx.x, w = tid >> 6, l = tid & 63;
  const int il = l & 15, kl = l >> 4;
  const int wm = w >> 1, wn = w & 1;
  ushort* o = Spb + ((size_t)z << 16);
#pragma unroll
  for (int fm = 0; fm < 8; ++fm)
#pragma unroll
    for (int fn = 0; fn < 4; ++fn) {
      int n = n0 + (wn << 6) + (fn << 4) + il;
#pragma unroll
      for (int j = 0; j < 4; ++j) {
        int m = (wm << 7) + (fm << 4) + (kl << 2) + j;
        o[(size_t)m * 256 + n] = f2bf(acc[fm][fn][j]);
      }
    }
}

// ------------------------- softmax (wave per row) ---------------------------
// P[bh][i][j] = softmax_j(sum_{ks=0..7} Spb[8bh+ks] / 64), bf16 with 1/sum.

__global__ void softmax_k(const ushort* __restrict__ Spb, ushort* __restrict__ Pb) {
  const int w = threadIdx.x >> 6, l = threadIdx.x & 63;
  const int row = (blockIdx.x << 2) + w;        // 0..8191
  const int bh = row >> 8, i = row & 255;
  const ushort4* p0 = reinterpret_cast<const ushort4*>(
      Spb + (((size_t)bh << 3) << 16) + ((size_t)i << 8)) + l;
  float s0 = 0.f, s1 = 0.f, s2 = 0.f, s3 = 0.f;
#pragma unroll
  for (int ks = 0; ks < 8; ++ks) {
    ushort4 a = p0[(size_t)ks * 16384];
    s0 += bf2f(a.x); s1 += bf2f(a.y); s2 += bf2f(a.z); s3 += bf2f(a.w);
  }
  const float scale = 0.015625f;
  s0 *= scale; s1 *= scale; s2 *= scale; s3 *= scale;
  float m = fmaxf(fmaxf(s0, s1), fmaxf(s2, s3));
#pragma unroll
  for (int d2 = 1; d2 < 64; d2 <<= 1) m = fmaxf(m, __shfl_xor(m, d2));
  float e0 = __expf(s0 - m), e1 = __expf(s1 - m);
  float e2 = __expf(s2 - m), e3 = __expf(s3 - m);
  float sum = e0 + e1 + e2 + e3;
#pragma unroll
  for (int d2 = 1; d2 < 64; d2 <<= 1) sum += __shfl_xor(sum, d2);
  float r = 1.0f / sum;
  ushort4 p; p.x = f2bf(e0 * r); p.y = f2bf(e1 * r);
  p.z = f2bf(e2 * r); p.w = f2bf(e3 * r);
  reinterpret_cast<ushort4*>(Pb + ((size_t)bh << 16) + ((size_t)i << 8))[l] = p;
}

// ---------------------- gemm_pv: O = P V  (A=Vt, B=P) -----------------------
// 1024 blocks; XCD swizzle groups one bh's 32 blocks on one XCD.

__global__ __launch_bounds__(256, 2) void gemm_pv_k(
    const ushort* __restrict__ Vt, const ushort* __restrict__ Pb,
    ushort* __restrict__ O2) {
  __shared__ __align__(16) char lds[73728];
  f32x4 acc[8][4];
  const int Bid = blockIdx.x;
  const int xcd = Bid & 7, idx = Bid >> 3;      // idx 0..127
  const int sub = idx & 31, grp = idx >> 5;     // sub: mt*2+nt, grp 0..3
  const int bh = (grp << 3) + xcd, b = bh >> 3, h = bh & 7;
  const int m0 = (sub >> 1) << 8;               // rd tile (16 x 256)
  const int n0 = (sub & 1) << 7;                // i tile (2 x 128)
  gemm_nt_256x128(Vt + ((size_t)bh << 20), Pb + ((size_t)bh << 16),
                  256, 256, 8, m0, n0, lds, acc);

  const int tid = threadIdx.x, w = tid >> 6, l = tid & 63;
  const int il = l & 15, kl = l >> 4;
  const int wm = w >> 1, wn = w & 1;
#pragma unroll
  for (int fm = 0; fm < 8; ++fm) {
    int rd0 = m0 + (wm << 7) + (fm << 4) + (kl << 2);
    int r = rd0 >> 6, d0 = rd0 & 63;
#pragma unroll
    for (int fn = 0; fn < 4; ++fn) {
      int i = n0 + (wn << 6) + (fn << 4) + il;
      ushort4 pk; pk.x = f2bf(acc[fm][fn][0]); pk.y = f2bf(acc[fm][fn][1]);
      pk.z = f2bf(acc[fm][fn][2]); pk.w = f2bf(acc[fm][fn][3]);
      *reinterpret_cast<ushort4*>(
          O2 + ((size_t)((((b << 6) + r) << 8) + i) << 9) + (h << 6) + d0) = pk;
    }
  }
}

// ------------------------------- launcher -----------------------------------

extern "C" void kernel_launch(void* const* d_in, const int* in_sizes, int n_in,
                              void* d_out, int out_size, void* d_ws, size_t ws_size,
                              hipStream_t stream) {
  const float* x    = (const float*)d_in[0];
  const float* Wqkv = (const float*)d_in[1];
  const float* W0   = (const float*)d_in[2];
  float* out = (float*)d_out;

  char* ws = (char*)d_ws;
  ushort* xb  = (ushort*)(ws);                    // 67,108,864 B (-> Spb -> O2)
  ushort* Wp  = (ushort*)(ws + 67108864);         //  1,572,864
  ushort* W0b = (ushort*)(ws + 68681728);         //    524,288
  ushort* Qb  = (ushort*)(ws + 69206016);         // 67,108,864 (-> Pb)
  ushort* Kb  = (ushort*)(ws + 136314880);        // 67,108,864
  ushort* Vt  = (ushort*)(ws + 203423744);        // 67,108,864  -> total 270,532,608
  if (ws_size < 270532608ull) return;             // workspace too small: fail visibly

  prep_all_k<<<2880, 256, 0, stream>>>(x, xb, Wqkv, Wp, W0, W0b);

  gemm_qkv_k<<<3072, 256, 0, stream>>>(xb, Wp, Qb, Kb, Vt);

  ushort* Spb = xb;                               // xb dead after gemm1 (33.6 MB)
  ushort* Pb  = Qb;                               // Qb dead after gemm_s (4.2 MB)
  ushort* O2  = xb;                               // Spb dead after softmax (64 MB)

  gemm_s_k<<<512, 256, 0, stream>>>(Qb, Kb, Spb);
  softmax_k<<<2048, 256, 0, stream>>>(Spb, Pb);
  gemm_pv_k<<<1024, 256, 0, stream>>>(Vt, Pb, O2);

  gemm_out_k<<<1024, 256, 0, stream>>>(O2, W0b, out);
}